// Round 2
// baseline (236.243 us; speedup 1.0000x reference)
//
#include <hip/hip_runtime.h>
#include <math.h>

// Problem constants (match reference setup_inputs)
#define BB 64       // batch
#define KK 4        // classes / time bins
#define CC 256      // feature dim
#define NN 8192     // bank entries per class
#define NROWS (KK*NN)        // 32768 bank rows
#define GRID_INTER 512       // 2 WGs per CU
#define WPG 4                // waves per WG
#define RPW 16               // rows per wave  (512*4*16 = 32768)
#define RPP 4                // rows per pass (amortize A2 LDS sweep)
#define NPASS (RPW/RPP)      // 4

// d_ws byte offsets
#define WS_A2_OFF    0        // 65536 B : float4 A2[cq=0..63][b=0..63]
#define WS_SLOT_OFF  65536    // 8192 B  : double slots[512][2] (ep,en per WG)
#define WS_NLL_OFF   73728    // 256 B   : float nll[64]
#define WS_INTRA_OFF 73984    // 256 B   : float intra[64]
#define WS_TKT_OFF   74240    // 4 B     : unsigned ticket

#define EPS_NLL 1e-7f

__device__ __forceinline__ float4 f4add(float4 a, float4 b){ return make_float4(a.x+b.x, a.y+b.y, a.z+b.z, a.w+b.w); }
__device__ __forceinline__ float4 f4scale(float4 a, float s){ return make_float4(a.x*s, a.y*s, a.z*s, a.w*s); }
__device__ __forceinline__ float dot4(float4 a, float4 b){ return a.x*b.x + a.y*b.y + a.z*b.z + a.w*b.w; }

__device__ __forceinline__ float wred(float v){
#pragma unroll
  for (int m = 32; m >= 1; m >>= 1) v += __shfl_xor(v, m, 64);
  return v;
}

// ---------------------------------------------------------------------------
// prep: per-b (64 blocks, 1 wave each)
//  - anchors = l2norm(mean_p(indiv)) -> stored TRANSPOSED as A2[cq][b] (float4)
//  - intra-modality loss term per b
//  - NLL surv term per b
// ---------------------------------------------------------------------------
__global__ __launch_bounds__(64) void prep_kernel(
    const float* __restrict__ hazards, const float* __restrict__ S,
    const float* __restrict__ indiv,   const float* __restrict__ gene,
    const float* __restrict__ path,    const int* __restrict__ label,
    const int* __restrict__ cvec,      char* __restrict__ ws)
{
  const int b = blockIdx.x;
  const int lane = threadIdx.x;          // 0..63, owns c = 4*lane .. 4*lane+3

  const float4* ind4 = (const float4*)indiv + (size_t)b * 256;  // [4][64] float4
  float4 i0 = ind4[  0 + lane];
  float4 i1 = ind4[ 64 + lane];
  float4 i2 = ind4[128 + lane];
  float4 i3 = ind4[192 + lane];
  float4 g  = ((const float4*)gene)[b*64 + lane];
  float4 p  = ((const float4*)path)[b*64 + lane];

  // anchor = l2norm(mean over the 4 components)
  float4 am = f4scale(f4add(f4add(i0, i1), f4add(i2, i3)), 0.25f);
  float na = sqrtf(wred(dot4(am, am)));
  float4 an = f4scale(am, 1.0f / fmaxf(na, 1e-12f));
  ((float4*)(ws + WS_A2_OFF))[lane*64 + b] = an;   // transposed layout

  // l2norm the 6 vectors (4 indiv comps, gene, path)
  float4 v[6] = {i0, i1, i2, i3, g, p};
#pragma unroll
  for (int j = 0; j < 6; ++j) {
    float n = sqrtf(wred(dot4(v[j], v[j])));
    v[j] = f4scale(v[j], 1.0f / fmaxf(n, 1e-12f));
  }

  // sims[p][t] = indiv_n[p] . gp_n[t]
  float s[4][2];
#pragma unroll
  for (int pp = 0; pp < 4; ++pp)
#pragma unroll
    for (int t = 0; t < 2; ++t)
      s[pp][t] = wred(dot4(v[pp], v[4+t]));

  if (lane == 0) {
    // MASK rows (common, synergy, g_spec, p_spec) x (gene, path):
    // [[1,1],[0,0],[1,0],[0,1]]; term = |s|*(1-m) - m*s
    float intra = (-s[0][0]) + (-s[0][1])
                + fabsf(s[1][0]) + fabsf(s[1][1])
                + (-s[2][0]) + fabsf(s[2][1])
                + fabsf(s[3][0]) + (-s[3][1]);
    intra = intra * 0.125f + 1.0f;
    ((float*)(ws + WS_INTRA_OFF))[b] = intra;

    // NLL surv (ALPHA = 0)
    int   Y  = label[b];
    float cf = (float)cvec[b];
    float s_y  = (Y == 0) ? 1.0f : S[b*KK + Y - 1];  // S_padded[Y]
    float s_y1 = S[b*KK + Y];                         // S_padded[Y+1]
    float h_y  = hazards[b*KK + Y];
    float neg_l = -cf * logf(fmaxf(s_y1, EPS_NLL))
                  - (1.0f - cf) * (logf(fmaxf(s_y, EPS_NLL)) + logf(fmaxf(h_y, EPS_NLL)));
    ((float*)(ws + WS_NLL_OFF))[b] = neg_l;
  }
}

// ---------------------------------------------------------------------------
// inter: stream cohort_bank (128 MiB), fused mean->l2norm->dot(anchors)->exp->sum
// lane = anchor index b; wave owns 16 contiguous rows (one class: 16 | 8192).
// RPP=4 rows per pass amortizes the 64 KB A2 LDS sweep to 16 KB/row.
// Last WG (ticket) folds in nll/intra and writes the final scalar.
// ---------------------------------------------------------------------------
__global__ __launch_bounds__(256, 2) void inter_kernel(
    const float* __restrict__ bank, const int* __restrict__ label,
    char* __restrict__ ws, float* __restrict__ out)
{
  __shared__ float4 A2s[4096];              // 64 KB: A2[cq][b]
  __shared__ float4 bns[WPG][RPP][64];      // 16 KB: per-wave normalized rows

  const int tid  = threadIdx.x;
  const int wave = tid >> 6;
  const int lane = tid & 63;

  // stage A2 into LDS
  const float4* A2g = (const float4*)(ws + WS_A2_OFF);
#pragma unroll
  for (int i = 0; i < 16; ++i) A2s[tid + i*256] = A2g[tid + i*256];
  __syncthreads();

  const int myLab = label[lane];
  const int gw    = blockIdx.x * WPG + wave;       // global wave id, 0..2047
  const int base  = gw * RPW;                       // first row of this wave
  const int kk    = base >> 13;                     // class of ALL this wave's rows
  const bool ispos = (myLab == kk);
  const float4* bank4 = (const float4*)bank;        // row stride = 256 float4

  float accE = 0.0f;                                // sum of exp(sim/TAU) this lane

#pragma unroll 1
  for (int pass = 0; pass < NPASS; ++pass) {
    const int row0 = base + pass * RPP;

    // load RPP rows, mean over 4 components (registers)
    float4 m[RPP];
#pragma unroll
    for (int r = 0; r < RPP; ++r) {
      const float4* rp = bank4 + (size_t)(row0 + r) * 256 + lane;
      float4 a0 = rp[0], a1 = rp[64], a2 = rp[128], a3 = rp[192];
      m[r] = f4scale(f4add(f4add(a0, a1), f4add(a2, a3)), 0.25f);
    }
    // l2norm each row -> this wave's LDS slice
#pragma unroll
    for (int r = 0; r < RPP; ++r) {
      float n = sqrtf(wred(dot4(m[r], m[r])));
      bns[wave][r][lane] = f4scale(m[r], 1.0f / fmaxf(n, 1e-12f));
    }
    // same-wave LDS RAW: compiler inserts lgkmcnt waits; no barrier needed.

    float s0 = 0.0f, s1 = 0.0f, s2 = 0.0f, s3 = 0.0f;
#pragma unroll 8
    for (int cq = 0; cq < 64; ++cq) {
      float4 a = A2s[cq*64 + lane];        // lane-contiguous, conflict-free
      s0 += dot4(a, bns[wave][0][cq]);     // uniform addr -> broadcast
      s1 += dot4(a, bns[wave][1][cq]);
      s2 += dot4(a, bns[wave][2][cq]);
      s3 += dot4(a, bns[wave][3][cq]);
    }

    accE += expf(s0 * 0.5f) + expf(s1 * 0.5f)      // TAU = 2
          + expf(s2 * 0.5f) + expf(s3 * 0.5f);
  }

  float epf = ispos ? accE : 0.0f;
  float enf = ispos ? 0.0f : accE;

  // wave reduce, stash per-wave partials in own (now dead) bns area
  epf = wred(epf);
  enf = wred(enf);
  if (lane == 0) {
    double* red = (double*)&bns[wave][0][0];
    red[0] = (double)epf;
    red[1] = (double)enf;
  }
  __syncthreads();

  double*   slots  = (double*)(ws + WS_SLOT_OFF);
  unsigned* ticket = (unsigned*)(ws + WS_TKT_OFF);
  volatile unsigned* tks = ((volatile unsigned*)&bns[0][0][0]) + 8;  // byte 32, clear of red[0..1]

  if (tid == 0) {
    double bep = 0.0, ben = 0.0;
#pragma unroll
    for (int w = 0; w < WPG; ++w) {
      double* rw = (double*)&bns[w][0][0];
      bep += rw[0]; ben += rw[1];
    }
    slots[blockIdx.x*2 + 0] = bep;
    slots[blockIdx.x*2 + 1] = ben;
    __threadfence();
    unsigned t = atomicAdd(ticket, 1u);
    *tks = t;
  }
  __syncthreads();

  if (*tks == GRID_INTER - 1 && wave == 0) {   // last WG finalizes
    __threadfence();
    double pep = 0.0, pen = 0.0;
    for (int i = lane; i < GRID_INTER; i += 64) {
      pep += slots[2*i + 0];
      pen += slots[2*i + 1];
    }
#pragma unroll
    for (int m = 32; m >= 1; m >>= 1) {
      pep += __shfl_xor(pep, m, 64);
      pen += __shfl_xor(pen, m, 64);
    }
    float scal = ((const float*)(ws + WS_NLL_OFF))[lane]
               + ((const float*)(ws + WS_INTRA_OFF))[lane];
    scal = wred(scal);
    if (lane == 0) {
      double ep = pep / (double)(BB * NN);              // mean over positives
      double en = pen / (double)(BB * (KK-1) * NN);     // mean over negatives
      double inter = -log((ep + 1e-8) / (ep + en + 1e-8));
      out[0] = (float)((double)scal / 64.0 + inter);
    }
  }
}

extern "C" void kernel_launch(void* const* d_in, const int* in_sizes, int n_in,
                              void* d_out, int out_size, void* d_ws, size_t ws_size,
                              hipStream_t stream)
{
  const float* hazards = (const float*)d_in[0];
  const float* S       = (const float*)d_in[1];
  const float* indiv   = (const float*)d_in[2];
  const float* gene    = (const float*)d_in[3];
  const float* path    = (const float*)d_in[4];
  const float* bank    = (const float*)d_in[5];
  const int*   label   = (const int*)d_in[6];
  const int*   cvec    = (const int*)d_in[7];
  char*  ws  = (char*)d_ws;
  float* out = (float*)d_out;

  hipMemsetAsync(ws + WS_TKT_OFF, 0, 4, stream);  // zero the ticket only
  prep_kernel<<<dim3(BB), dim3(64), 0, stream>>>(hazards, S, indiv, gene, path, label, cvec, ws);
  inter_kernel<<<dim3(GRID_INTER), dim3(256), 0, stream>>>(bank, label, ws, out);
}

// Round 3
// 233.845 us; speedup vs baseline: 1.0103x; 1.0103x over previous
//
#include <hip/hip_runtime.h>
#include <math.h>

// Problem constants (match reference setup_inputs)
#define BB 64       // batch
#define KK 4        // classes / time bins
#define CC 256      // feature dim
#define NN 8192     // bank entries per class
#define NROWS (KK*NN)        // 32768 bank rows
#define GRID_INTER 512       // WGs
#define WPG 8                // waves per WG (512 threads)
#define RPW 8                // rows per wave (512*8*8 = 32768)
#define RPP 4                // rows per pass
#define NPASS (RPW/RPP)      // 2

// d_ws byte offsets
#define WS_A2_OFF    0        // 65536 B : float4 A2[cq=0..63][b=0..63]
#define WS_SLOT_OFF  65536    // 8192 B  : double slots[512][2] (ep,en per WG)
#define WS_NLL_OFF   73728    // 256 B   : float nll[64]
#define WS_INTRA_OFF 73984    // 256 B   : float intra[64]
#define WS_TKT_OFF   74240    // 4 B     : unsigned ticket

#define EPS_NLL 1e-7f

__device__ __forceinline__ float4 f4add(float4 a, float4 b){ return make_float4(a.x+b.x, a.y+b.y, a.z+b.z, a.w+b.w); }
__device__ __forceinline__ float4 f4scale(float4 a, float s){ return make_float4(a.x*s, a.y*s, a.z*s, a.w*s); }
__device__ __forceinline__ float dot4(float4 a, float4 b){ return a.x*b.x + a.y*b.y + a.z*b.z + a.w*b.w; }

__device__ __forceinline__ float wred(float v){
#pragma unroll
  for (int m = 32; m >= 1; m >>= 1) v += __shfl_xor(v, m, 64);
  return v;
}

// wave-uniform lane read: float from lane l -> scalar (v_readlane_b32)
__device__ __forceinline__ float rl(float v, int l){
  return __uint_as_float(__builtin_amdgcn_readlane(__float_as_uint(v), l));
}

// ---------------------------------------------------------------------------
// prep: per-b (64 blocks, 1 wave each)
// ---------------------------------------------------------------------------
__global__ __launch_bounds__(64) void prep_kernel(
    const float* __restrict__ hazards, const float* __restrict__ S,
    const float* __restrict__ indiv,   const float* __restrict__ gene,
    const float* __restrict__ path,    const int* __restrict__ label,
    const int* __restrict__ cvec,      char* __restrict__ ws)
{
  const int b = blockIdx.x;
  const int lane = threadIdx.x;          // 0..63, owns c = 4*lane .. 4*lane+3

  const float4* ind4 = (const float4*)indiv + (size_t)b * 256;  // [4][64] float4
  float4 i0 = ind4[  0 + lane];
  float4 i1 = ind4[ 64 + lane];
  float4 i2 = ind4[128 + lane];
  float4 i3 = ind4[192 + lane];
  float4 g  = ((const float4*)gene)[b*64 + lane];
  float4 p  = ((const float4*)path)[b*64 + lane];

  // anchor = l2norm(mean over the 4 components)
  float4 am = f4scale(f4add(f4add(i0, i1), f4add(i2, i3)), 0.25f);
  float na = sqrtf(wred(dot4(am, am)));
  float4 an = f4scale(am, 1.0f / fmaxf(na, 1e-12f));
  ((float4*)(ws + WS_A2_OFF))[lane*64 + b] = an;   // transposed layout

  // l2norm the 6 vectors (4 indiv comps, gene, path)
  float4 v[6] = {i0, i1, i2, i3, g, p};
#pragma unroll
  for (int j = 0; j < 6; ++j) {
    float n = sqrtf(wred(dot4(v[j], v[j])));
    v[j] = f4scale(v[j], 1.0f / fmaxf(n, 1e-12f));
  }

  // sims[p][t] = indiv_n[p] . gp_n[t]
  float s[4][2];
#pragma unroll
  for (int pp = 0; pp < 4; ++pp)
#pragma unroll
    for (int t = 0; t < 2; ++t)
      s[pp][t] = wred(dot4(v[pp], v[4+t]));

  if (lane == 0) {
    // MASK rows (common, synergy, g_spec, p_spec) x (gene, path):
    // [[1,1],[0,0],[1,0],[0,1]]; term = |s|*(1-m) - m*s
    float intra = (-s[0][0]) + (-s[0][1])
                + fabsf(s[1][0]) + fabsf(s[1][1])
                + (-s[2][0]) + fabsf(s[2][1])
                + fabsf(s[3][0]) + (-s[3][1]);
    intra = intra * 0.125f + 1.0f;
    ((float*)(ws + WS_INTRA_OFF))[b] = intra;

    // NLL surv (ALPHA = 0)
    int   Y  = label[b];
    float cf = (float)cvec[b];
    float s_y  = (Y == 0) ? 1.0f : S[b*KK + Y - 1];  // S_padded[Y]
    float s_y1 = S[b*KK + Y];                         // S_padded[Y+1]
    float h_y  = hazards[b*KK + Y];
    float neg_l = -cf * logf(fmaxf(s_y1, EPS_NLL))
                  - (1.0f - cf) * (logf(fmaxf(s_y, EPS_NLL)) + logf(fmaxf(h_y, EPS_NLL)));
    ((float*)(ws + WS_NLL_OFF))[b] = neg_l;
  }
}

// ---------------------------------------------------------------------------
// inter v3: occupancy-first. WG=512 (8 waves), LDS = A2 only (64 KB) ->
// 2 WGs/CU = 16 waves/CU. bn values cross lanes via v_readlane (SGPR) into
// FMA — no LDS broadcasts, no bns buffer. Wave owns 8 contiguous rows.
// ---------------------------------------------------------------------------
__global__ __launch_bounds__(512, 4) void inter_kernel(
    const float* __restrict__ bank, const int* __restrict__ label,
    char* __restrict__ ws, float* __restrict__ out)
{
  __shared__ float4 A2s[4096];              // 64 KB: A2[cq][b]
  __shared__ double redw[WPG][2];           // per-wave partials
  __shared__ unsigned tkt_s;

  const int tid  = threadIdx.x;
  const int wave = tid >> 6;
  const int lane = tid & 63;

  // stage A2 into LDS (512 threads x 8 iters)
  const float4* A2g = (const float4*)(ws + WS_A2_OFF);
#pragma unroll
  for (int i = 0; i < 8; ++i) A2s[tid + i*512] = A2g[tid + i*512];
  __syncthreads();

  const int myLab = label[lane];
  const int gw    = blockIdx.x * WPG + wave;   // global wave id, 0..4095
  const int base  = gw * RPW;                   // first row of this wave
  const int kk    = base >> 13;                 // class of ALL 8 rows (8 | 8192)
  const bool ispos = (myLab == kk);
  const float4* bank4 = (const float4*)bank;    // row stride = 256 float4

  float accE = 0.0f;

#pragma unroll 1
  for (int pass = 0; pass < NPASS; ++pass) {
    const int row0 = base + pass * RPP;

    // load RPP rows, mean over 4 components -> registers
    float4 m[RPP];
#pragma unroll
    for (int r = 0; r < RPP; ++r) {
      const float4* rp = bank4 + (size_t)(row0 + r) * 256 + lane;
      float4 a0 = rp[0], a1 = rp[64], a2 = rp[128], a3 = rp[192];
      m[r] = f4scale(f4add(f4add(a0, a1), f4add(a2, a3)), 0.25f);
    }
    // l2norm each row in-register
#pragma unroll
    for (int r = 0; r < RPP; ++r) {
      float n = sqrtf(wred(dot4(m[r], m[r])));
      m[r] = f4scale(m[r], 1.0f / fmaxf(n, 1e-12f));
    }

    // sims: lane = anchor b. bn[cq] chunks come from lane cq's registers
    // via v_readlane -> SGPR operand in FMA. A2 chunk from LDS (2-way, free).
    float s0 = 0.0f, s1 = 0.0f, s2 = 0.0f, s3 = 0.0f;
#pragma unroll 4
    for (int cq = 0; cq < 64; ++cq) {
      float4 a = A2s[cq*64 + lane];
      s0 += a.x*rl(m[0].x,cq) + a.y*rl(m[0].y,cq) + a.z*rl(m[0].z,cq) + a.w*rl(m[0].w,cq);
      s1 += a.x*rl(m[1].x,cq) + a.y*rl(m[1].y,cq) + a.z*rl(m[1].z,cq) + a.w*rl(m[1].w,cq);
      s2 += a.x*rl(m[2].x,cq) + a.y*rl(m[2].y,cq) + a.z*rl(m[2].z,cq) + a.w*rl(m[2].w,cq);
      s3 += a.x*rl(m[3].x,cq) + a.y*rl(m[3].y,cq) + a.z*rl(m[3].z,cq) + a.w*rl(m[3].w,cq);
    }

    accE += expf(s0 * 0.5f) + expf(s1 * 0.5f)      // TAU = 2
          + expf(s2 * 0.5f) + expf(s3 * 0.5f);
  }

  float epf = ispos ? accE : 0.0f;
  float enf = ispos ? 0.0f : accE;
  epf = wred(epf);
  enf = wred(enf);
  if (lane == 0) {
    redw[wave][0] = (double)epf;
    redw[wave][1] = (double)enf;
  }
  __syncthreads();

  double*   slots  = (double*)(ws + WS_SLOT_OFF);
  unsigned* ticket = (unsigned*)(ws + WS_TKT_OFF);

  if (tid == 0) {
    double bep = 0.0, ben = 0.0;
#pragma unroll
    for (int w = 0; w < WPG; ++w) { bep += redw[w][0]; ben += redw[w][1]; }
    slots[blockIdx.x*2 + 0] = bep;
    slots[blockIdx.x*2 + 1] = ben;
    __threadfence();
    tkt_s = atomicAdd(ticket, 1u);
  }
  __syncthreads();

  if (tkt_s == GRID_INTER - 1 && wave == 0) {   // last WG finalizes
    __threadfence();
    double pep = 0.0, pen = 0.0;
    for (int i = lane; i < GRID_INTER; i += 64) {
      pep += slots[2*i + 0];
      pen += slots[2*i + 1];
    }
#pragma unroll
    for (int m = 32; m >= 1; m >>= 1) {
      pep += __shfl_xor(pep, m, 64);
      pen += __shfl_xor(pen, m, 64);
    }
    float scal = ((const float*)(ws + WS_NLL_OFF))[lane]
               + ((const float*)(ws + WS_INTRA_OFF))[lane];
    scal = wred(scal);
    if (lane == 0) {
      double ep = pep / (double)(BB * NN);              // mean over positives
      double en = pen / (double)(BB * (KK-1) * NN);     // mean over negatives
      double inter = -log((ep + 1e-8) / (ep + en + 1e-8));
      out[0] = (float)((double)scal / 64.0 + inter);
    }
  }
}

extern "C" void kernel_launch(void* const* d_in, const int* in_sizes, int n_in,
                              void* d_out, int out_size, void* d_ws, size_t ws_size,
                              hipStream_t stream)
{
  const float* hazards = (const float*)d_in[0];
  const float* S       = (const float*)d_in[1];
  const float* indiv   = (const float*)d_in[2];
  const float* gene    = (const float*)d_in[3];
  const float* path    = (const float*)d_in[4];
  const float* bank    = (const float*)d_in[5];
  const int*   label   = (const int*)d_in[6];
  const int*   cvec    = (const int*)d_in[7];
  char*  ws  = (char*)d_ws;
  float* out = (float*)d_out;

  hipMemsetAsync(ws + WS_TKT_OFF, 0, 4, stream);  // zero the ticket only
  prep_kernel<<<dim3(BB), dim3(64), 0, stream>>>(hazards, S, indiv, gene, path, label, cvec, ws);
  inter_kernel<<<dim3(GRID_INTER), dim3(512), 0, stream>>>(bank, label, ws, out);
}